// Round 1
// baseline (437.552 us; speedup 1.0000x reference)
//
#include <hip/hip_runtime.h>
#include <hip/hip_bf16.h>
#include <stdint.h>
#include <stddef.h>

// ---------------- problem constants ----------------
#define B_ 4
#define T_ 2048
#define C_ 1024
#define H_ 16
#define D_ 64
#define M_ (B_ * T_)   // 8192 rows of x

typedef __bf16 bf16x8 __attribute__((ext_vector_type(8)));
typedef float  f32x4  __attribute__((ext_vector_type(4)));
typedef unsigned short u16x8 __attribute__((ext_vector_type(8)));
typedef unsigned short u16x4 __attribute__((ext_vector_type(4)));

__device__ __forceinline__ unsigned short f2bf(float f) {
    // round-to-nearest-even fp32 -> bf16
    union { float f; unsigned int u; } c; c.f = f;
    unsigned int u = c.u;
    unsigned int r = (u + 0x7fffu + ((u >> 16) & 1u)) >> 16;
    return (unsigned short)r;
}

__device__ __forceinline__ bf16x8 ld_bf16x8(const unsigned short* p) {
    u16x8 v = *(const u16x8*)p;
    return __builtin_bit_cast(bf16x8, v);
}

// ============================================================
// Kernel 1: y = x @ W^T + b for W in {Wq,Wk,Wv}, fused over N=3072.
// Inputs fp32, converted to bf16 during LDS staging, bf16 MFMA, fp32 acc.
// q,k stored [B,H,T,D] bf16; v stored transposed [B,H,D,T] bf16.
// Tile 128x128, BK=32, 4 waves (2x2 of 64x64), 16x16x32 MFMA.
// ============================================================
#define TM 128
#define TN 128
#define BK 32
#define LDT 40   // LDS row stride in u16 (80 B: 16B-aligned, conflict-benign)

__global__ __launch_bounds__(256)
void qkv_gemm(const float* __restrict__ x,
              const float* __restrict__ Wq, const float* __restrict__ bq,
              const float* __restrict__ Wk, const float* __restrict__ bk,
              const float* __restrict__ Wv, const float* __restrict__ bv,
              unsigned short* __restrict__ qo,
              unsigned short* __restrict__ ko,
              unsigned short* __restrict__ vo)
{
    __shared__ unsigned short As[TM * LDT];
    __shared__ unsigned short Bs[TN * LDT];

    const int tid   = threadIdx.x;
    const int bm    = blockIdx.x;          // 0..63
    const int bn    = blockIdx.y;          // 0..23  (concat N: 8 q, 8 k, 8 v)
    const int which = bn >> 3;             // 0=q 1=k 2=v (block-uniform)
    const int n_base = (bn & 7) * TN;
    const int m_base = bm * TM;

    const float* W    = (which == 0) ? Wq : (which == 1) ? Wk : Wv;
    const float* bias = (which == 0) ? bq : (which == 1) ? bk : bv;

    const int wave = tid >> 6, lane = tid & 63;
    const int wr = wave >> 1, wc = wave & 1;      // 2x2 waves -> 64x64 each
    const int ln = lane & 15, quad = lane >> 4;

    // staging: 8 threads/row (float4 each), 32 rows/pass, 4 passes
    const int sr = tid >> 3;           // 0..31
    const int sc = (tid & 7) * 4;      // 0..28

    const f32x4 fz = {0.f, 0.f, 0.f, 0.f};
    f32x4 acc[4][4];
#pragma unroll
    for (int i = 0; i < 4; ++i)
#pragma unroll
        for (int j = 0; j < 4; ++j) acc[i][j] = fz;

    for (int k0 = 0; k0 < C_; k0 += BK) {
#pragma unroll
        for (int p = 0; p < 4; ++p) {
            const int r = sr + p * 32;
            f32x4 a = *(const f32x4*)(&x[(size_t)(m_base + r) * C_ + k0 + sc]);
            f32x4 b = *(const f32x4*)(&W[(size_t)(n_base + r) * C_ + k0 + sc]);
            u16x4 ap = { f2bf(a.x), f2bf(a.y), f2bf(a.z), f2bf(a.w) };
            u16x4 bp = { f2bf(b.x), f2bf(b.y), f2bf(b.z), f2bf(b.w) };
            *(u16x4*)(&As[r * LDT + sc]) = ap;
            *(u16x4*)(&Bs[r * LDT + sc]) = bp;
        }
        __syncthreads();

        bf16x8 af[4], bfr[4];
#pragma unroll
        for (int mi = 0; mi < 4; ++mi)
            af[mi] = ld_bf16x8(&As[(wr * 64 + mi * 16 + ln) * LDT + quad * 8]);
#pragma unroll
        for (int ni = 0; ni < 4; ++ni)
            bfr[ni] = ld_bf16x8(&Bs[(wc * 64 + ni * 16 + ln) * LDT + quad * 8]);
#pragma unroll
        for (int mi = 0; mi < 4; ++mi)
#pragma unroll
            for (int ni = 0; ni < 4; ++ni)
                acc[mi][ni] = __builtin_amdgcn_mfma_f32_16x16x32_bf16(
                    af[mi], bfr[ni], acc[mi][ni], 0, 0, 0);
        __syncthreads();
    }

    // epilogue: +bias, ->bf16, scatter to head-split layouts
#pragma unroll
    for (int ni = 0; ni < 4; ++ni) {
        const int n_local = n_base + wc * 64 + ni * 16 + ln;   // 0..1023
        const float bv_ = bias[n_local];
        const int h = n_local >> 6, d = n_local & 63;
#pragma unroll
        for (int mi = 0; mi < 4; ++mi) {
            const int m0 = m_base + wr * 64 + mi * 16 + quad * 4;  // rows m0..m0+3
            const int b  = m0 >> 11;         // /T_
            const int t0 = m0 & (T_ - 1);
            f32x4 v = acc[mi][ni];
            if (which == 2) {
                // v transposed: [B,H,D,T]; 4 consecutive t -> one 8B store
                u16x4 pk = { f2bf(v.x + bv_), f2bf(v.y + bv_),
                             f2bf(v.z + bv_), f2bf(v.w + bv_) };
                *(u16x4*)(&vo[((size_t)(b * H_ + h) * D_ + d) * T_ + t0]) = pk;
            } else {
                unsigned short* dst =
                    ((which == 0) ? qo : ko) + ((size_t)(b * H_ + h) * T_ + t0) * (size_t)D_ + d;
                dst[0 * D_] = f2bf(v.x + bv_);
                dst[1 * D_] = f2bf(v.y + bv_);
                dst[2 * D_] = f2bf(v.z + bv_);
                dst[3 * D_] = f2bf(v.w + bv_);
            }
        }
    }
}

// ============================================================
// Kernel 2: flash attention. One block = one (b,h) x 64 Q-rows.
// 4 waves x 16 rows. BN=64 KV tile. Online softmax, P via LDS.
// ============================================================
#define LDK 72   // 64 data + 8 pad u16 -> 144 B rows (16B-aligned)

__global__ __launch_bounds__(256)
void flash_attn(const unsigned short* __restrict__ qb,
                const unsigned short* __restrict__ kb,
                const unsigned short* __restrict__ vtb,
                float* __restrict__ out)
{
    __shared__ unsigned short Ks[64 * LDK];  // [kv][d]
    __shared__ unsigned short Vs[64 * LDK];  // [d][kv]  (from transposed v)
    __shared__ unsigned short Ps[64 * LDK];  // [m][kv]

    const int tid = threadIdx.x;
    const int qt  = blockIdx.x;   // 0..31 (Q tile)
    const int bh  = blockIdx.y;   // 0..63
    const int b   = bh >> 4, h = bh & 15;

    const int wave = tid >> 6, lane = tid & 63;
    const int ln = lane & 15, quad = lane >> 4;

    const unsigned short* Qb = qb  + (size_t)bh * T_ * D_;
    const unsigned short* Kb = kb  + (size_t)bh * T_ * D_;
    const unsigned short* Vb = vtb + (size_t)bh * D_ * T_;

    // Q fragments live in registers for the whole block
    const int qrow = qt * 64 + wave * 16 + ln;
    const bf16x8 qf0 = ld_bf16x8(&Qb[(size_t)qrow * D_ + quad * 8]);
    const bf16x8 qf1 = ld_bf16x8(&Qb[(size_t)qrow * D_ + 32 + quad * 8]);

    const f32x4 fz = {0.f, 0.f, 0.f, 0.f};
    float m_i[4], l_i[4];
    f32x4 acc_o[4];
#pragma unroll
    for (int r = 0; r < 4; ++r) { m_i[r] = -1e30f; l_i[r] = 0.f; }
#pragma unroll
    for (int dt = 0; dt < 4; ++dt) acc_o[dt] = fz;

    // staging: 4 threads/row, each 2x16B
    const int sr   = tid >> 2;          // 0..63
    const int scol = (tid & 3) * 16;    // 0,16,32,48
    const float scale = 0.125f;         // 1/sqrt(64)

    for (int kv0 = 0; kv0 < T_; kv0 += 64) {
        __syncthreads();
        *(u16x8*)(&Ks[sr * LDK + scol])     = *(const u16x8*)(&Kb[(size_t)(kv0 + sr) * D_ + scol]);
        *(u16x8*)(&Ks[sr * LDK + scol + 8]) = *(const u16x8*)(&Kb[(size_t)(kv0 + sr) * D_ + scol + 8]);
        *(u16x8*)(&Vs[sr * LDK + scol])     = *(const u16x8*)(&Vb[(size_t)sr * T_ + kv0 + scol]);
        *(u16x8*)(&Vs[sr * LDK + scol + 8]) = *(const u16x8*)(&Vb[(size_t)sr * T_ + kv0 + scol + 8]);
        __syncthreads();

        // S = (Q K^T) * scale   (rows: quad*4+r, cols: nt*16+ln)
        f32x4 s[4];
#pragma unroll
        for (int nt = 0; nt < 4; ++nt) {
            bf16x8 kf0 = ld_bf16x8(&Ks[(nt * 16 + ln) * LDK + quad * 8]);
            bf16x8 kf1 = ld_bf16x8(&Ks[(nt * 16 + ln) * LDK + 32 + quad * 8]);
            f32x4 c = fz;
            c = __builtin_amdgcn_mfma_f32_16x16x32_bf16(qf0, kf0, c, 0, 0, 0);
            c = __builtin_amdgcn_mfma_f32_16x16x32_bf16(qf1, kf1, c, 0, 0, 0);
            s[nt] = c * scale;
        }

        // online softmax
        float alpha[4], rsum[4];
#pragma unroll
        for (int r = 0; r < 4; ++r) {
            float mx = fmaxf(fmaxf(s[0][r], s[1][r]), fmaxf(s[2][r], s[3][r]));
#pragma unroll
            for (int off = 1; off < 16; off <<= 1) mx = fmaxf(mx, __shfl_xor(mx, off));
            float nm = fmaxf(m_i[r], mx);
            alpha[r] = __expf(m_i[r] - nm);
            m_i[r] = nm;
            rsum[r] = 0.f;
        }
#pragma unroll
        for (int nt = 0; nt < 4; ++nt)
#pragma unroll
            for (int r = 0; r < 4; ++r) {
                float p = __expf(s[nt][r] - m_i[r]);
                rsum[r] += p;
                Ps[(wave * 16 + quad * 4 + r) * LDK + nt * 16 + ln] = f2bf(p);
            }
#pragma unroll
        for (int r = 0; r < 4; ++r) {
#pragma unroll
            for (int off = 1; off < 16; off <<= 1) rsum[r] += __shfl_xor(rsum[r], off);
            l_i[r] = l_i[r] * alpha[r] + rsum[r];
        }
#pragma unroll
        for (int dt = 0; dt < 4; ++dt) {
            acc_o[dt][0] *= alpha[0]; acc_o[dt][1] *= alpha[1];
            acc_o[dt][2] *= alpha[2]; acc_o[dt][3] *= alpha[3];
        }
        __syncthreads();   // P LDS write -> A-frag read

        // O += P V
        bf16x8 pf0 = ld_bf16x8(&Ps[(wave * 16 + ln) * LDK + quad * 8]);
        bf16x8 pf1 = ld_bf16x8(&Ps[(wave * 16 + ln) * LDK + 32 + quad * 8]);
#pragma unroll
        for (int dt = 0; dt < 4; ++dt) {
            bf16x8 vf0 = ld_bf16x8(&Vs[(dt * 16 + ln) * LDK + quad * 8]);
            bf16x8 vf1 = ld_bf16x8(&Vs[(dt * 16 + ln) * LDK + 32 + quad * 8]);
            acc_o[dt] = __builtin_amdgcn_mfma_f32_16x16x32_bf16(pf0, vf0, acc_o[dt], 0, 0, 0);
            acc_o[dt] = __builtin_amdgcn_mfma_f32_16x16x32_bf16(pf1, vf1, acc_o[dt], 0, 0, 0);
        }
    }

    // epilogue: out[b, t, h*64 + d] fp32
#pragma unroll
    for (int dt = 0; dt < 4; ++dt)
#pragma unroll
        for (int r = 0; r < 4; ++r) {
            const int t = qt * 64 + wave * 16 + quad * 4 + r;
            const int c = h * 64 + dt * 16 + ln;
            out[(size_t)(b * T_ + t) * C_ + c] = acc_o[dt][r] / l_i[r];
        }
}

// ============================================================
extern "C" void kernel_launch(void* const* d_in, const int* in_sizes, int n_in,
                              void* d_out, int out_size, void* d_ws, size_t ws_size,
                              hipStream_t stream) {
    const float* q_x = (const float*)d_in[0];
    const float* Wq  = (const float*)d_in[1];
    const float* bq  = (const float*)d_in[2];
    const float* Wk  = (const float*)d_in[3];
    const float* bk  = (const float*)d_in[4];
    const float* Wv  = (const float*)d_in[5];
    const float* bv  = (const float*)d_in[6];
    float* out = (float*)d_out;

    // workspace: q [B,H,T,D] | k [B,H,T,D] | vT [B,H,D,T], all bf16
    const size_t elems = (size_t)M_ * C_;   // 8,388,608 per tensor
    unsigned short* qb  = (unsigned short*)d_ws;
    unsigned short* kb  = qb + elems;
    unsigned short* vtb = kb + elems;
    (void)ws_size; (void)in_sizes; (void)n_in; (void)out_size;

    qkv_gemm<<<dim3(M_ / TM, 3 * C_ / TN), 256, 0, stream>>>(
        q_x, Wq, bq, Wk, bk, Wv, bv, qb, kb, vtb);

    flash_attn<<<dim3(T_ / 64, B_ * H_), 256, 0, stream>>>(qb, kb, vtb, out);
}

// Round 3
// 314.983 us; speedup vs baseline: 1.3891x; 1.3891x over previous
//
#include <hip/hip_runtime.h>
#include <hip/hip_bf16.h>
#include <stdint.h>
#include <stddef.h>

// ---------------- problem constants ----------------
#define B_ 4
#define T_ 2048
#define C_ 1024
#define H_ 16
#define D_ 64
#define M_ (B_ * T_)   // 8192 rows of x

typedef __bf16 bf16x8 __attribute__((ext_vector_type(8)));
typedef float  f32x4  __attribute__((ext_vector_type(4)));
typedef short  s16x4  __attribute__((ext_vector_type(4)));
typedef unsigned short u16x8 __attribute__((ext_vector_type(8)));
typedef unsigned short u16x4 __attribute__((ext_vector_type(4)));

__device__ __forceinline__ unsigned short f2bf(float f) {
    union { float f; unsigned int u; } c; c.f = f;
    unsigned int u = c.u;
    unsigned int r = (u + 0x7fffu + ((u >> 16) & 1u)) >> 16;
    return (unsigned short)r;
}

__device__ __forceinline__ bf16x8 ld_bf16x8(const unsigned short* p) {
    u16x8 v = *(const u16x8*)p;
    return __builtin_bit_cast(bf16x8, v);
}

// async global -> LDS, 16 B per lane (dest = uniform base + lane*16)
__device__ __forceinline__ void gl_lds16(const unsigned short* g, unsigned short* l) {
    __builtin_amdgcn_global_load_lds(
        (const void __attribute__((address_space(1)))*)g,
        (void __attribute__((address_space(3)))*)l, 16, 0, 0);
}

__device__ __forceinline__ f32x4 mfma16(s16x4 a, s16x4 b, f32x4 c) {
#if __has_builtin(__builtin_amdgcn_mfma_f32_16x16x16bf16_1k)
    return __builtin_amdgcn_mfma_f32_16x16x16bf16_1k(a, b, c, 0, 0, 0);
#else
    asm volatile("v_mfma_f32_16x16x16_bf16 %0, %1, %2, %0"
                 : "+v"(c) : "v"(a), "v"(b));
    return c;
#endif
}

// ============================================================
// Kernel 0: fp32 -> bf16 conversion of x and {Wq,Wk,Wv} (concat).
// ============================================================
#define X4_ ((int64_t)M_ * C_ / 4)   // 2,097,152 float4s
#define W4_ ((int64_t)C_ * C_ / 4)   //   262,144 float4s per W

__global__ __launch_bounds__(256)
void cvt_bf16(const float* __restrict__ x,
              const float* __restrict__ Wq, const float* __restrict__ Wk,
              const float* __restrict__ Wv,
              unsigned short* __restrict__ xb, unsigned short* __restrict__ wb)
{
    const int64_t i4 = (int64_t)blockIdx.x * blockDim.x + threadIdx.x;
    const float* src; unsigned short* dst; int64_t off;
    if (i4 < X4_) { src = x; dst = xb; off = i4; }
    else {
        int64_t j = i4 - X4_;
        int which = (int)(j / W4_);
        off = j - (int64_t)which * W4_;
        src = (which == 0) ? Wq : (which == 1) ? Wk : Wv;
        dst = wb + (int64_t)which * C_ * C_;
    }
    f32x4 v = *(const f32x4*)(src + off * 4);
    u16x4 o = { f2bf(v.x), f2bf(v.y), f2bf(v.z), f2bf(v.w) };
    *(u16x4*)(dst + off * 4) = o;
}

// ============================================================
// Kernel 1: y = xb @ Wb^T + b, N concat = 3072. Pure bf16, m97-style
// global_load_lds(16B) staging into unpadded [128][32] LDS tiles.
// q,k stored [B,H,T,D] bf16; v stored transposed [B,H,D,T] bf16.
// ============================================================
__global__ __launch_bounds__(256)
void qkv_gemm(const unsigned short* __restrict__ xb,
              const unsigned short* __restrict__ wb,
              const float* __restrict__ bq, const float* __restrict__ bk,
              const float* __restrict__ bv,
              unsigned short* __restrict__ qo,
              unsigned short* __restrict__ ko,
              unsigned short* __restrict__ vo)
{
    __shared__ alignas(16) unsigned short As[128 * 32];
    __shared__ alignas(16) unsigned short Bs[128 * 32];

    const int tid   = threadIdx.x;
    const int bm    = blockIdx.x;          // 0..63
    const int bn    = blockIdx.y;          // 0..23
    const int which = bn >> 3;             // 0=q 1=k 2=v
    const int n_base = (bn & 7) * 128;     // within the selected matrix
    const int nrow   = bn * 128;           // within concat wb
    const int m_base = bm * 128;

    const float* bias = (which == 0) ? bq : (which == 1) ? bk : bv;

    const int w = tid >> 6, lane = tid & 63;
    const int wr = w >> 1, wc = w & 1;
    const int ln = lane & 15, quad = lane >> 4;

    const int srow = (lane >> 2);          // 0..15
    const int scu  = (lane & 3) * 8;       // u16 offset within 64-B row

    const f32x4 fz = {0.f, 0.f, 0.f, 0.f};
    f32x4 acc[4][4];
#pragma unroll
    for (int i = 0; i < 4; ++i)
#pragma unroll
        for (int j = 0; j < 4; ++j) acc[i][j] = fz;

    for (int k0 = 0; k0 < C_; k0 += 32) {
        __syncthreads();
        const int r0 = (w * 2 + 0) * 16 + srow;
        const int r1 = (w * 2 + 1) * 16 + srow;
        gl_lds16(xb + (size_t)(m_base + r0) * C_ + k0 + scu, As + (w * 2 + 0) * 512);
        gl_lds16(xb + (size_t)(m_base + r1) * C_ + k0 + scu, As + (w * 2 + 1) * 512);
        gl_lds16(wb + (size_t)(nrow + r0) * C_ + k0 + scu, Bs + (w * 2 + 0) * 512);
        gl_lds16(wb + (size_t)(nrow + r1) * C_ + k0 + scu, Bs + (w * 2 + 1) * 512);
        __syncthreads();

        bf16x8 af[4], bfr[4];
#pragma unroll
        for (int mi = 0; mi < 4; ++mi)
            af[mi] = ld_bf16x8(&As[(wr * 64 + mi * 16 + ln) * 32 + quad * 8]);
#pragma unroll
        for (int ni = 0; ni < 4; ++ni)
            bfr[ni] = ld_bf16x8(&Bs[(wc * 64 + ni * 16 + ln) * 32 + quad * 8]);
#pragma unroll
        for (int mi = 0; mi < 4; ++mi)
#pragma unroll
            for (int ni = 0; ni < 4; ++ni)
                acc[mi][ni] = __builtin_amdgcn_mfma_f32_16x16x32_bf16(
                    af[mi], bfr[ni], acc[mi][ni], 0, 0, 0);
    }

#pragma unroll
    for (int ni = 0; ni < 4; ++ni) {
        const int n_local = n_base + wc * 64 + ni * 16 + ln;   // 0..1023
        const float bv_ = bias[n_local];
        const int h = n_local >> 6, d = n_local & 63;
#pragma unroll
        for (int mi = 0; mi < 4; ++mi) {
            const int m0 = m_base + wr * 64 + mi * 16 + quad * 4;
            const int b  = m0 >> 11;
            const int t0 = m0 & (T_ - 1);
            f32x4 v = acc[mi][ni];
            if (which == 2) {
                u16x4 pk = { f2bf(v.x + bv_), f2bf(v.y + bv_),
                             f2bf(v.z + bv_), f2bf(v.w + bv_) };
                *(u16x4*)(&vo[((size_t)(b * H_ + h) * D_ + d) * T_ + t0]) = pk;
            } else {
                unsigned short* dst =
                    ((which == 0) ? qo : ko) + ((size_t)(b * H_ + h) * T_ + t0) * (size_t)D_ + d;
                dst[0 * D_] = f2bf(v.x + bv_);
                dst[1 * D_] = f2bf(v.y + bv_);
                dst[2 * D_] = f2bf(v.z + bv_);
                dst[3 * D_] = f2bf(v.w + bv_);
            }
        }
    }
}

// ============================================================
// Kernel 2: flash attention, S^T formulation (P stays in registers).
// S^T = K·Q^T via 16x16x32; its C-layout (col=q, row=kv) IS the
// B-operand layout of 16x16x16, so O^T = V^T·P^T needs no LDS transpose.
// K/V staged via swizzled global_load_lds: LDS[r][c] = src[r][c^(r&7)]
// (16-B chunks) -> all fragment reads bank-conflict-benign.
// ============================================================
__global__ __launch_bounds__(256)
void flash_attn(const unsigned short* __restrict__ qb,
                const unsigned short* __restrict__ kb,
                const unsigned short* __restrict__ vtb,
                float* __restrict__ out)
{
    __shared__ alignas(16) unsigned char smem[64 * 68 * 4];  // 17408 B
    unsigned short* Ks = (unsigned short*)smem;              // [64][64] swz
    unsigned short* Vs = (unsigned short*)(smem + 8192);     // [64][64] swz (d-major)
    float* Os = (float*)smem;                                // [64][68] epilogue

    const int tid = threadIdx.x;
    const int qt  = blockIdx.x;   // 0..31
    const int bh  = blockIdx.y;   // 0..63
    const int b   = bh >> 4, h = bh & 15;

    const int w = tid >> 6, lane = tid & 63;
    const int ln = lane & 15, quad = lane >> 4;

    const unsigned short* Qb = qb  + (size_t)bh * T_ * D_;
    const unsigned short* Kb = kb  + (size_t)bh * T_ * D_;
    const unsigned short* Vb = vtb + (size_t)bh * D_ * T_;

    // Q as B-operand fragments (n = Q-row = ln, k = d = quad*8+j)
    const int qrow = qt * 64 + w * 16 + ln;
    const bf16x8 qf0 = ld_bf16x8(&Qb[(size_t)qrow * D_ + quad * 8]);
    const bf16x8 qf1 = ld_bf16x8(&Qb[(size_t)qrow * D_ + 32 + quad * 8]);

    // staging geometry: instr i of wave w -> 8 rows of 128 B
    const int srow0 = w * 16 + (lane >> 3);          // i=0 rows
    const int srow1 = srow0 + 8;                     // i=1 rows
    const int schunk = (lane & 7) ^ (lane >> 3);     // swizzled source chunk
    const int scu = schunk * 8;                      // u16 offset

    const f32x4 fz = {0.f, 0.f, 0.f, 0.f};
    float m2 = -3.0e38f, l_i = 0.f;
    f32x4 acc[4];                 // O^T: row d = dt*16+quad*4+r, col q = ln
#pragma unroll
    for (int dt = 0; dt < 4; ++dt) acc[dt] = fz;

    const float k1 = 0.125f * 1.44269504089f;   // (1/sqrt(D)) * log2(e)

    for (int kv0 = 0; kv0 < T_; kv0 += 64) {
        __syncthreads();
        gl_lds16(Kb + (size_t)(kv0 + srow0) * D_ + scu, Ks + (w * 2 + 0) * 512);
        gl_lds16(Kb + (size_t)(kv0 + srow1) * D_ + scu, Ks + (w * 2 + 1) * 512);
        gl_lds16(Vb + (size_t)srow0 * T_ + kv0 + scu,   Vs + (w * 2 + 0) * 512);
        gl_lds16(Vb + (size_t)srow1 * T_ + kv0 + scu,   Vs + (w * 2 + 1) * 512);
        __syncthreads();

        // S^T tiles: A = K (m=kv), B = Q (n=q)
        f32x4 s[4];
#pragma unroll
        for (int kvt = 0; kvt < 4; ++kvt) {
            const int r_ = kvt * 16 + ln;               // kv row; r_&7 == ln&7
            bf16x8 kf0 = ld_bf16x8(&Ks[r_ * 64 + ((quad)     ^ (ln & 7)) * 8]);
            bf16x8 kf1 = ld_bf16x8(&Ks[r_ * 64 + ((quad + 4) ^ (ln & 7)) * 8]);
            f32x4 c = fz;
            c = __builtin_amdgcn_mfma_f32_16x16x32_bf16(kf0, qf0, c, 0, 0, 0);
            c = __builtin_amdgcn_mfma_f32_16x16x32_bf16(kf1, qf1, c, 0, 0, 0);
            s[kvt] = c * k1;   // now in log2 domain
        }

        // online softmax (per lane: one q-column, 16 kv values)
        f32x4 mm;
        mm.x = fmaxf(fmaxf(s[0].x, s[1].x), fmaxf(s[2].x, s[3].x));
        mm.y = fmaxf(fmaxf(s[0].y, s[1].y), fmaxf(s[2].y, s[3].y));
        mm.z = fmaxf(fmaxf(s[0].z, s[1].z), fmaxf(s[2].z, s[3].z));
        mm.w = fmaxf(fmaxf(s[0].w, s[1].w), fmaxf(s[2].w, s[3].w));
        float mx = fmaxf(fmaxf(mm.x, mm.y), fmaxf(mm.z, mm.w));
        mx = fmaxf(mx, __shfl_xor(mx, 16));
        mx = fmaxf(mx, __shfl_xor(mx, 32));

        const float nm = fmaxf(m2, mx);
        const float alpha = __builtin_amdgcn_exp2f(m2 - nm);
        m2 = nm;

        float rs = 0.f;
        s16x4 pk[4];
#pragma unroll
        for (int kvt = 0; kvt < 4; ++kvt) {
#pragma unroll
            for (int r = 0; r < 4; ++r) {
                float p = __builtin_amdgcn_exp2f(s[kvt][r] - m2);
                rs += p;
                pk[kvt][r] = (short)f2bf(p);
            }
        }
        rs += __shfl_xor(rs, 16);
        rs += __shfl_xor(rs, 32);
        l_i = l_i * alpha + rs;

#pragma unroll
        for (int dt = 0; dt < 4; ++dt) acc[dt] *= alpha;

        // O^T += V^T · P^T  (A = V^T frag, B = P^T from registers)
#pragma unroll
        for (int dt = 0; dt < 4; ++dt) {
            const int vr = dt * 16 + ln;                // d row; vr&7 == ln&7
#pragma unroll
            for (int kvt = 0; kvt < 4; ++kvt) {
                const int c = (kvt * 2 + (quad >> 1)) ^ (ln & 7);
                u16x4 vv = *(const u16x4*)(&Vs[vr * 64 + c * 8 + (quad & 1) * 4]);
                acc[dt] = mfma16(__builtin_bit_cast(s16x4, vv), pk[kvt], acc[dt]);
            }
        }
    }

    // epilogue: normalize, transpose O^T -> O via LDS, coalesced stores
    __syncthreads();
    const float rinv = 1.0f / l_i;
#pragma unroll
    for (int dt = 0; dt < 4; ++dt)
#pragma unroll
        for (int r = 0; r < 4; ++r)
            Os[(w * 16 + ln) * 68 + dt * 16 + quad * 4 + r] = acc[dt][r] * rinv;
    __syncthreads();

    const int q  = tid >> 2;
    const int c0 = (tid & 3) * 16;
    const float* src = &Os[q * 68 + c0];
    float* dst = &out[((size_t)(b * T_ + qt * 64 + q)) * C_ + h * 64 + c0];
#pragma unroll
    for (int i = 0; i < 4; ++i)
        *(f32x4*)(dst + i * 4) = *(const f32x4*)(src + i * 4);
}

// ============================================================
extern "C" void kernel_launch(void* const* d_in, const int* in_sizes, int n_in,
                              void* d_out, int out_size, void* d_ws, size_t ws_size,
                              hipStream_t stream) {
    const float* q_x = (const float*)d_in[0];
    const float* Wq  = (const float*)d_in[1];
    const float* bq  = (const float*)d_in[2];
    const float* Wk  = (const float*)d_in[3];
    const float* bk  = (const float*)d_in[4];
    const float* Wv  = (const float*)d_in[5];
    const float* bv  = (const float*)d_in[6];
    float* out = (float*)d_out;

    const size_t elems = (size_t)M_ * C_;      // 8,388,608
    unsigned short* xb  = (unsigned short*)d_ws;
    unsigned short* wb  = xb + elems;                    // 3*C*C
    unsigned short* qb  = wb + (size_t)3 * C_ * C_;
    unsigned short* kb  = qb + elems;
    unsigned short* vtb = kb + elems;
    (void)ws_size; (void)in_sizes; (void)n_in; (void)out_size;

    const int64_t total4 = X4_ + 3 * W4_;      // 2,883,584
    cvt_bf16<<<(int)(total4 / 256), 256, 0, stream>>>(q_x, Wq, Wk, Wv, xb, wb);

    qkv_gemm<<<dim3(M_ / 128, 24), 256, 0, stream>>>(
        xb, wb, bq, bk, bv, qb, kb, vtb);

    flash_attn<<<dim3(T_ / 64, B_ * H_), 256, 0, stream>>>(qb, kb, vtb, out);
}